// Round 1
// baseline (1144.428 us; speedup 1.0000x reference)
//
#include <hip/hip_runtime.h>

typedef unsigned short u16;
typedef unsigned int u32;
typedef __attribute__((ext_vector_type(8))) __bf16 bf16x8;
typedef __attribute__((ext_vector_type(4))) float f32x4;

// ---------- helpers ----------

__device__ __forceinline__ u16 f2bf(float f) {
    union { float f; u32 u; } v; v.f = f;
    u32 r = v.u + 0x7FFFu + ((v.u >> 16) & 1u);   // RNE
    return (u16)(r >> 16);
}

__device__ __forceinline__ void gload16(const void* g, void* l) {
    __builtin_amdgcn_global_load_lds(
        (const __attribute__((address_space(1))) u32*)g,
        (__attribute__((address_space(3))) u32*)l,
        16, 0, 0);
}

// ---------- V^T -> bf16 (tiled transpose + convert) ----------
// Vt[j][k] = bf16(V[k][j]), n = 3072
__global__ __launch_bounds__(256) void transpose_conv(
    const float* __restrict__ V, u16* __restrict__ Vt, int n) {
    __shared__ float tile[64][65];
    const int k0 = blockIdx.y * 64, j0 = blockIdx.x * 64;
    const int t = threadIdx.x;
    const int r = t >> 4, c4 = t & 15;
#pragma unroll
    for (int i = 0; i < 4; i++) {
        int row = i * 16 + r;
        const float4 v = *(const float4*)&V[(size_t)(k0 + row) * n + j0 + c4 * 4];
        tile[row][c4 * 4 + 0] = v.x;
        tile[row][c4 * 4 + 1] = v.y;
        tile[row][c4 * 4 + 2] = v.z;
        tile[row][c4 * 4 + 3] = v.w;
    }
    __syncthreads();
#pragma unroll
    for (int i = 0; i < 4; i++) {
        int row = i * 16 + r;  // local j
        ushort4 o;
        o.x = f2bf(tile[c4 * 4 + 0][row]);
        o.y = f2bf(tile[c4 * 4 + 1][row]);
        o.z = f2bf(tile[c4 * 4 + 2][row]);
        o.w = f2bf(tile[c4 * 4 + 3][row]);
        *(ushort4*)&Vt[(size_t)(j0 + row) * n + k0 + c4 * 4] = o;
    }
}

// ---------- NT GEMM: C[m,n] = sum_k A32[m,k]*(scale_k)*B16[n,k] ----------
// A fp32 row-major [M,K] (converted to bf16 in staging, optional Sp scale),
// B bf16 row-major [N,K] via global_load_lds, C fp32 [M,N].
// 128x128 tile, BK=64, 256 threads = 4 waves, 4x4 16x16x32 MFMAs per wave.
template <bool USE_SCALE>
__global__ __launch_bounds__(256) void gemm_nt_bf16(
    const float* __restrict__ A, const u16* __restrict__ B,
    float* __restrict__ C, const float* __restrict__ S,
    const float* __restrict__ Dl, int M, int N, int K) {
    __shared__ u16 As[128 * 64];
    __shared__ u16 Bs[128 * 64];
    const int t = threadIdx.x;
    const int m0 = blockIdx.y * 128, n0 = blockIdx.x * 128;
    const int wave = t >> 6, lane = t & 63;
    const int quad = lane >> 4, lrow = lane & 15;
    const int wm = (wave >> 1) * 64, wn = (wave & 1) * 64;
    const int r = t >> 4, c4 = t & 15;
    f32x4 acc[4][4] = {};

    const int nK = K >> 6;
    for (int kb = 0; kb < nK; kb++) {
        const int kbase = kb * 64;
        // --- B tile: async global->LDS, 16B per lane, 4 issues ---
#pragma unroll
        for (int i = 0; i < 4; i++) {
            const u16* g = B + (size_t)(n0 + i * 32 + (t >> 3)) * K + kbase + (t & 7) * 8;
            gload16(g, (char*)Bs + i * 4096 + t * 16);
        }
        // --- A tile: fp32 load -> (scale) -> bf16 -> LDS ---
        float4 sv;
        if (USE_SCALE) {
            const float4 s4 = *(const float4*)&S[kbase + c4 * 4];
            const float4 d4 = *(const float4*)&Dl[kbase + c4 * 4];
            sv.x = fmaxf(s4.x + d4.x, 0.f);
            sv.y = fmaxf(s4.y + d4.y, 0.f);
            sv.z = fmaxf(s4.z + d4.z, 0.f);
            sv.w = fmaxf(s4.w + d4.w, 0.f);
        }
#pragma unroll
        for (int i = 0; i < 8; i++) {
            int row = i * 16 + r;
            float4 v = *(const float4*)&A[(size_t)(m0 + row) * K + kbase + c4 * 4];
            if (USE_SCALE) { v.x *= sv.x; v.y *= sv.y; v.z *= sv.z; v.w *= sv.w; }
            ushort4 p;
            p.x = f2bf(v.x); p.y = f2bf(v.y); p.z = f2bf(v.z); p.w = f2bf(v.w);
            *(ushort4*)&As[row * 64 + c4 * 4] = p;
        }
        __syncthreads();
        // --- compute: two K=32 steps ---
#pragma unroll
        for (int kk = 0; kk < 2; kk++) {
            bf16x8 af[4], bfr[4];
#pragma unroll
            for (int mi = 0; mi < 4; mi++)
                af[mi] = *(const bf16x8*)&As[(wm + mi * 16 + lrow) * 64 + kk * 32 + quad * 8];
#pragma unroll
            for (int ni = 0; ni < 4; ni++)
                bfr[ni] = *(const bf16x8*)&Bs[(wn + ni * 16 + lrow) * 64 + kk * 32 + quad * 8];
#pragma unroll
            for (int mi = 0; mi < 4; mi++)
#pragma unroll
                for (int ni = 0; ni < 4; ni++)
                    acc[mi][ni] = __builtin_amdgcn_mfma_f32_16x16x32_bf16(
                        af[mi], bfr[ni], acc[mi][ni], 0, 0, 0);
        }
        __syncthreads();
    }
    // --- epilogue: C/D layout col=lane&15, row=quad*4+reg ---
#pragma unroll
    for (int mi = 0; mi < 4; mi++) {
#pragma unroll
        for (int rr = 0; rr < 4; rr++) {
            int row = m0 + wm + mi * 16 + quad * 4 + rr;
            float* cp = C + (size_t)row * N + n0 + wn + lrow;
#pragma unroll
            for (int ni = 0; ni < 4; ni++) cp[ni * 16] = acc[mi][ni][rr];
        }
    }
}

// ---------- Kron apply: WtT[o,:] = bf16( (Q1 (x) Q2 (x) Q3) @ W[o,:] ) ----------
// index d = d1*192 + d2*12 + d3  (q1=16, q2=16, q3=12)
__global__ __launch_bounds__(256) void kron_apply(
    const float* __restrict__ W, const float* __restrict__ Q1,
    const float* __restrict__ Q2, const float* __restrict__ Q3,
    u16* __restrict__ WtT) {
    __shared__ float T0[3072], T1[3072];
    __shared__ float Q1s[256], Q2s[256], Q3s[144];
    const int o = blockIdx.x, t = threadIdx.x;
#pragma unroll
    for (int i = 0; i < 12; i++) T0[t + i * 256] = W[(size_t)o * 3072 + t + i * 256];
    Q1s[t] = Q1[t];
    Q2s[t] = Q2[t];
    if (t < 144) Q3s[t] = Q3[t];
    __syncthreads();
    // mode-1: T1[d1, j2, j3] = sum_j1 Q1[d1,j1] * T0[j1, j2, j3]
#pragma unroll
    for (int i = 0; i < 12; i++) {
        int e = t + i * 256;
        int d1 = e / 192, rem = e % 192;
        float s = 0.f;
#pragma unroll
        for (int j1 = 0; j1 < 16; j1++) s += Q1s[d1 * 16 + j1] * T0[j1 * 192 + rem];
        T1[e] = s;
    }
    __syncthreads();
    // mode-2: T2[d1, d2, j3] = sum_j2 Q2[d2,j2] * T1[d1, j2, j3]   (T2 reuses T0)
#pragma unroll
    for (int i = 0; i < 12; i++) {
        int e = t + i * 256;
        int j3 = e % 12, d2 = (e / 12) & 15, d1 = e / 192;
        float s = 0.f;
#pragma unroll
        for (int j2 = 0; j2 < 16; j2++) s += Q2s[d2 * 16 + j2] * T1[d1 * 192 + j2 * 12 + j3];
        T0[e] = s;
    }
    __syncthreads();
    // mode-3: y[d1,d2,d3] = sum_j3 Q3[d3,j3] * T2[d1,d2,j3]
#pragma unroll
    for (int i = 0; i < 12; i++) {
        int e = t + i * 256;
        int d3 = e % 12, b = e - d3;
        float s = 0.f;
#pragma unroll
        for (int j3 = 0; j3 < 12; j3++) s += Q3s[d3 * 12 + j3] * T0[b + j3];
        WtT[(size_t)o * 3072 + e] = f2bf(s);
    }
}

// ---------- launch ----------
extern "C" void kernel_launch(void* const* d_in, const int* in_sizes, int n_in,
                              void* d_out, int out_size, void* d_ws, size_t ws_size,
                              hipStream_t stream) {
    const float* x   = (const float*)d_in[0];  // [4,4096,3072]
    const float* U   = (const float*)d_in[1];  // [3072,3072]
    const float* S   = (const float*)d_in[2];  // [3072]
    const float* V   = (const float*)d_in[3];  // [3072,3072]
    const float* dl  = (const float*)d_in[4];  // [3072]
    const float* Q1  = (const float*)d_in[5];  // [16,16]
    const float* Q2  = (const float*)d_in[6];  // [16,16]
    const float* Q3  = (const float*)d_in[7];  // [12,12]
    float* out = (float*)d_out;                // [16384,3072]

    char* ws = (char*)d_ws;
    u16*   Vt  = (u16*)ws;                                   // 3072*3072 bf16 = 18.9 MB
    float* W   = (float*)(ws + 18874368);                    // 3072*3072 f32  = 37.7 MB
    u16*   WtT = (u16*)(ws + 18874368 + 37748736);           // 3072*3072 bf16 = 18.9 MB

    // 1) Vt = bf16(V^T)
    hipLaunchKernelGGL(transpose_conv, dim3(48, 48), dim3(256), 0, stream, V, Vt, 3072);
    // 2) W = (U * relu(S+delta)) @ V      (NT with B = Vt)
    hipLaunchKernelGGL((gemm_nt_bf16<true>), dim3(24, 24), dim3(256), 0, stream,
                       U, Vt, W, S, dl, 3072, 3072, 3072);
    // 3) WtT[o,d] = (kron(Q1,Q2,Q3) @ W[o,:])[d]
    hipLaunchKernelGGL(kron_apply, dim3(3072), dim3(256), 0, stream, W, Q1, Q2, Q3, WtT);
    // 4) out = x @ W_t                    (NT with B = WtT)
    hipLaunchKernelGGL((gemm_nt_bf16<false>), dim3(24, 128), dim3(256), 0, stream,
                       x, WtT, out, nullptr, nullptr, 16384, 3072, 3072);
}

// Round 2
// 960.108 us; speedup vs baseline: 1.1920x; 1.1920x over previous
//
#include <hip/hip_runtime.h>

typedef unsigned short u16;
typedef unsigned int u32;
typedef __attribute__((ext_vector_type(8))) __bf16 bf16x8;
typedef __attribute__((ext_vector_type(4))) float f32x4;
typedef __attribute__((ext_vector_type(8))) u16 u16x8;

// ---------- helpers ----------

__device__ __forceinline__ u16 f2bf(float f) {
    union { float f; u32 u; } v; v.f = f;
    u32 r = v.u + 0x7FFFu + ((v.u >> 16) & 1u);   // RNE
    return (u16)(r >> 16);
}

__device__ __forceinline__ void gload16(const void* g, void* l) {
    __builtin_amdgcn_global_load_lds(
        (const __attribute__((address_space(1))) u32*)g,
        (__attribute__((address_space(3))) u32*)l,
        16, 0, 0);
}

// ---------- fp32 -> bf16 elementwise (8 elems/thread) ----------
__global__ __launch_bounds__(256) void conv_bf16(
    const float* __restrict__ in, u16* __restrict__ out) {
    const size_t i = (size_t)blockIdx.x * 256 + threadIdx.x;
    const float4 a = ((const float4*)in)[i * 2];
    const float4 b = ((const float4*)in)[i * 2 + 1];
    u16x8 o;
    o[0] = f2bf(a.x); o[1] = f2bf(a.y); o[2] = f2bf(a.z); o[3] = f2bf(a.w);
    o[4] = f2bf(b.x); o[5] = f2bf(b.y); o[6] = f2bf(b.z); o[7] = f2bf(b.w);
    ((u16x8*)out)[i] = o;
}

// ---------- Ub[m,k] = bf16(U[m,k] * relu(S[k]+delta[k])) ----------
__global__ __launch_bounds__(64) void conv_scale(
    const float* __restrict__ U, const float* __restrict__ S,
    const float* __restrict__ D, u16* __restrict__ out) {
    const int m = blockIdx.y;
    const int k = (blockIdx.x * 64 + threadIdx.x) * 8;
    const size_t base = (size_t)m * 3072 + k;
    const float4 a = *(const float4*)&U[base];
    const float4 b = *(const float4*)&U[base + 4];
    const float4 s1 = *(const float4*)&S[k], s2 = *(const float4*)&S[k + 4];
    const float4 d1 = *(const float4*)&D[k], d2 = *(const float4*)&D[k + 4];
    u16x8 o;
    o[0] = f2bf(a.x * fmaxf(s1.x + d1.x, 0.f));
    o[1] = f2bf(a.y * fmaxf(s1.y + d1.y, 0.f));
    o[2] = f2bf(a.z * fmaxf(s1.z + d1.z, 0.f));
    o[3] = f2bf(a.w * fmaxf(s1.w + d1.w, 0.f));
    o[4] = f2bf(b.x * fmaxf(s2.x + d2.x, 0.f));
    o[5] = f2bf(b.y * fmaxf(s2.y + d2.y, 0.f));
    o[6] = f2bf(b.z * fmaxf(s2.z + d2.z, 0.f));
    o[7] = f2bf(b.w * fmaxf(s2.w + d2.w, 0.f));
    *(u16x8*)&out[base] = o;
}

// ---------- V^T -> bf16 (tiled transpose + convert) ----------
__global__ __launch_bounds__(256) void transpose_conv(
    const float* __restrict__ V, u16* __restrict__ Vt, int n) {
    __shared__ float tile[64][65];
    const int k0 = blockIdx.y * 64, j0 = blockIdx.x * 64;
    const int t = threadIdx.x;
    const int r = t >> 4, c4 = t & 15;
#pragma unroll
    for (int i = 0; i < 4; i++) {
        int row = i * 16 + r;
        const float4 v = *(const float4*)&V[(size_t)(k0 + row) * n + j0 + c4 * 4];
        tile[row][c4 * 4 + 0] = v.x;
        tile[row][c4 * 4 + 1] = v.y;
        tile[row][c4 * 4 + 2] = v.z;
        tile[row][c4 * 4 + 3] = v.w;
    }
    __syncthreads();
#pragma unroll
    for (int i = 0; i < 4; i++) {
        int row = i * 16 + r;  // local j
        ushort4 o;
        o.x = f2bf(tile[c4 * 4 + 0][row]);
        o.y = f2bf(tile[c4 * 4 + 1][row]);
        o.z = f2bf(tile[c4 * 4 + 2][row]);
        o.w = f2bf(tile[c4 * 4 + 3][row]);
        *(ushort4*)&Vt[(size_t)(j0 + row) * n + k0 + c4 * 4] = o;
    }
}

// ---------- bf16 NT GEMM: C[m,n] = sum_k A[m,k]*B[n,k], fp32 out ----------
// 128x128 tile, BK=64, 4 waves, 4x4 16x16x32 MFMAs/wave.
// Both operands staged via global_load_lds (16B). LDS is XOR-swizzled:
// 16B-chunk c stored at c^(row&7) — applied on the GLOBAL source address
// (lds dst must stay lane-contiguous), de-applied at the fragment read.
// Fragment reads then hit all 32 banks at 8 dwords/bank (conflict-free).
__global__ __launch_bounds__(256) void gemm_bt(
    const u16* __restrict__ A, const u16* __restrict__ B,
    float* __restrict__ C, int M, int N, int K) {
    __shared__ u16 As[128 * 64];
    __shared__ u16 Bs[128 * 64];
    const int t = threadIdx.x;
    const int m0 = blockIdx.y * 128, n0 = blockIdx.x * 128;
    const int wave = t >> 6, lane = t & 63;
    const int quad = lane >> 4, lrow = lane & 15;
    const int wm = (wave >> 1) * 64, wn = (wave & 1) * 64;
    const int gr = t >> 3;                    // staging row 0..31 (per issue)
    const int gc = (t & 7) ^ (gr & 7);        // swizzled source chunk
    const int c0 = (quad ^ (lrow & 7)) * 8;   // u16 offset of kk=0 fragment chunk
    f32x4 acc[4][4] = {};

    const u16* Ag = A + (size_t)(m0 + gr) * K + gc * 8;
    const u16* Bg = B + (size_t)(n0 + gr) * K + gc * 8;

    for (int kb = 0; kb < K; kb += 64) {
#pragma unroll
        for (int i = 0; i < 4; i++) {
            gload16(Ag + (size_t)i * 32 * K + kb, (char*)As + i * 4096 + t * 16);
            gload16(Bg + (size_t)i * 32 * K + kb, (char*)Bs + i * 4096 + t * 16);
        }
        __syncthreads();
#pragma unroll
        for (int kk = 0; kk < 2; kk++) {
            const int co = c0 ^ (kk * 32);
            bf16x8 af[4], bfr[4];
#pragma unroll
            for (int mi = 0; mi < 4; mi++)
                af[mi] = *(const bf16x8*)&As[(wm + mi * 16 + lrow) * 64 + co];
#pragma unroll
            for (int ni = 0; ni < 4; ni++)
                bfr[ni] = *(const bf16x8*)&Bs[(wn + ni * 16 + lrow) * 64 + co];
#pragma unroll
            for (int mi = 0; mi < 4; mi++)
#pragma unroll
                for (int ni = 0; ni < 4; ni++)
                    acc[mi][ni] = __builtin_amdgcn_mfma_f32_16x16x32_bf16(
                        af[mi], bfr[ni], acc[mi][ni], 0, 0, 0);
        }
        __syncthreads();
    }
    // epilogue: C/D layout col=lane&15, row=quad*4+reg
#pragma unroll
    for (int mi = 0; mi < 4; mi++) {
#pragma unroll
        for (int rr = 0; rr < 4; rr++) {
            int row = m0 + wm + mi * 16 + quad * 4 + rr;
            float* cp = C + (size_t)row * N + n0 + wn + lrow;
#pragma unroll
            for (int ni = 0; ni < 4; ni++) cp[ni * 16] = acc[mi][ni][rr];
        }
    }
}

// ---------- Kron apply: WtT[o,:] = bf16( (Q1 (x) Q2 (x) Q3) @ W[o,:] ) ----------
__global__ __launch_bounds__(256) void kron_apply(
    const float* __restrict__ W, const float* __restrict__ Q1,
    const float* __restrict__ Q2, const float* __restrict__ Q3,
    u16* __restrict__ WtT) {
    __shared__ float T0[3072], T1[3072];
    __shared__ float Q1s[256], Q2s[256], Q3s[144];
    const int o = blockIdx.x, t = threadIdx.x;
#pragma unroll
    for (int i = 0; i < 12; i++) T0[t + i * 256] = W[(size_t)o * 3072 + t + i * 256];
    Q1s[t] = Q1[t];
    Q2s[t] = Q2[t];
    if (t < 144) Q3s[t] = Q3[t];
    __syncthreads();
#pragma unroll
    for (int i = 0; i < 12; i++) {
        int e = t + i * 256;
        int d1 = e / 192, rem = e % 192;
        float s = 0.f;
#pragma unroll
        for (int j1 = 0; j1 < 16; j1++) s += Q1s[d1 * 16 + j1] * T0[j1 * 192 + rem];
        T1[e] = s;
    }
    __syncthreads();
#pragma unroll
    for (int i = 0; i < 12; i++) {
        int e = t + i * 256;
        int j3 = e % 12, d2 = (e / 12) & 15, d1 = e / 192;
        float s = 0.f;
#pragma unroll
        for (int j2 = 0; j2 < 16; j2++) s += Q2s[d2 * 16 + j2] * T1[d1 * 192 + j2 * 12 + j3];
        T0[e] = s;
    }
    __syncthreads();
#pragma unroll
    for (int i = 0; i < 12; i++) {
        int e = t + i * 256;
        int d3 = e % 12, b = e - d3;
        float s = 0.f;
#pragma unroll
        for (int j3 = 0; j3 < 12; j3++) s += Q3s[d3 * 12 + j3] * T0[b + j3];
        WtT[(size_t)o * 3072 + e] = f2bf(s);
    }
}

// ---------- launch ----------
extern "C" void kernel_launch(void* const* d_in, const int* in_sizes, int n_in,
                              void* d_out, int out_size, void* d_ws, size_t ws_size,
                              hipStream_t stream) {
    const float* x   = (const float*)d_in[0];  // [4,4096,3072]
    const float* U   = (const float*)d_in[1];  // [3072,3072]
    const float* S   = (const float*)d_in[2];  // [3072]
    const float* V   = (const float*)d_in[3];  // [3072,3072]
    const float* dl  = (const float*)d_in[4];  // [3072]
    const float* Q1  = (const float*)d_in[5];  // [16,16]
    const float* Q2  = (const float*)d_in[6];  // [16,16]
    const float* Q3  = (const float*)d_in[7];  // [12,12]
    float* out = (float*)d_out;                // [16384,3072]

    char* ws = (char*)d_ws;
    u16*   xb  = (u16*)ws;                                    // 100,663,296 B
    u16*   Ub  = (u16*)(ws + 100663296);                      //  18,874,368 B
    u16*   Vt  = (u16*)(ws + 100663296 + 18874368);           //  18,874,368 B
    float* W   = (float*)(ws + 100663296 + 2 * 18874368);     //  37,748,736 B
    u16*   WtT = Ub;  // alias: Ub is dead once gemm1 completes

    // 1) xb = bf16(x)   (16384*3072/8 = 6,291,456 threads)
    hipLaunchKernelGGL(conv_bf16, dim3(24576), dim3(256), 0, stream, x, xb);
    // 2) Ub = bf16(U * relu(S+delta))
    hipLaunchKernelGGL(conv_scale, dim3(6, 3072), dim3(64), 0, stream, U, S, dl, Ub);
    // 3) Vt = bf16(V^T)
    hipLaunchKernelGGL(transpose_conv, dim3(48, 48), dim3(256), 0, stream, V, Vt, 3072);
    // 4) W = Ub @ Vt^T  (= (U*Sp) @ V)
    hipLaunchKernelGGL(gemm_bt, dim3(24, 24), dim3(256), 0, stream,
                       Ub, Vt, W, 3072, 3072, 3072);
    // 5) WtT[o,:] = bf16(kron(Q1,Q2,Q3) @ W[o,:])
    hipLaunchKernelGGL(kron_apply, dim3(3072), dim3(256), 0, stream, W, Q1, Q2, Q3, WtT);
    // 6) out = xb @ WtT^T  (= x @ W_t)
    hipLaunchKernelGGL(gemm_bt, dim3(24, 128), dim3(256), 0, stream,
                       xb, WtT, out, 16384, 3072, 3072);
}